// Round 1
// baseline (82.118 us; speedup 1.0000x reference)
//
#include <hip/hip_runtime.h>
#include <hip/hip_bf16.h>

#define NNODES 50000
#define DEG 16
#define NEDGES (NNODES * DEG)
#define IND 512
#define OUTD 128

#define BM 128
#define BK 64
#define NB 128          // nodes per block in edge kernel
#define SROWS 144       // staged h rows per block (NB + DEG)

typedef __attribute__((ext_vector_type(8))) short bf16x8;
typedef __attribute__((ext_vector_type(4))) float f32x4;

static __device__ __forceinline__ unsigned short f2bf(float f) {
    // round-to-nearest-even f32 -> bf16 (inputs are finite; no NaN handling needed)
    unsigned u = __builtin_bit_cast(unsigned, f);
    u += 0x7fffu + ((u >> 16) & 1u);
    return (unsigned short)(u >> 16);
}

// ---------------- kernel 0: W [512][128] f32 -> Wt [128][512] bf16 ----------------
__global__ __launch_bounds__(256) void wt_kernel(const float* __restrict__ W,
                                                 unsigned short* __restrict__ Wt) {
    int flat = blockIdx.x * 256 + threadIdx.x;   // 16384 total = 128 n * 128 k4
    int n  = flat >> 7;
    int k4 = flat & 127;
    int k0 = k4 * 4;
    unsigned short v0 = f2bf(W[(k0 + 0) * OUTD + n]);
    unsigned short v1 = f2bf(W[(k0 + 1) * OUTD + n]);
    unsigned short v2 = f2bf(W[(k0 + 2) * OUTD + n]);
    unsigned short v3 = f2bf(W[(k0 + 3) * OUTD + n]);
    uint2 o;
    o.x = (unsigned)v0 | ((unsigned)v1 << 16);
    o.y = (unsigned)v2 | ((unsigned)v3 << 16);
    *reinterpret_cast<uint2*>(&Wt[n * IND + k0]) = o;   // coalesced 8B stores
}

// ---------------- kernel 1: h = x @ W  (bf16 MFMA, f32 accum) ----------------
// block: 256 thr (4 waves, 2x2), tile 128x128, K-chunks of 64.
// A_lds[row][k] bf16, B_lds[col][k] bf16, both XOR-swizzled: byte ^= (row&7)<<4.
__global__ __launch_bounds__(256) void gemm_kernel(const float* __restrict__ x,
                                                   const unsigned short* __restrict__ Wt,
                                                   float* __restrict__ h) {
    __shared__ __align__(16) unsigned char Al[BM * BK * 2];    // 16 KB
    __shared__ __align__(16) unsigned char Bl[OUTD * BK * 2];  // 16 KB

    const int tid  = threadIdx.x;
    const int base = blockIdx.x * BM;
    const int lane = tid & 63;
    const int wid  = tid >> 6;
    const int wr   = (wid >> 1) * 64;
    const int wc   = (wid & 1) * 64;
    const int l15  = lane & 15;
    const int kg   = lane >> 4;

    f32x4 zero = {0.f, 0.f, 0.f, 0.f};
    f32x4 acc[4][4];
#pragma unroll
    for (int mt = 0; mt < 4; ++mt)
#pragma unroll
        for (int nt = 0; nt < 4; ++nt) acc[mt][nt] = zero;

    for (int ch = 0; ch < 8; ++ch) {
        const int k0 = ch * BK;
        // stage A: 128 rows x 64 k, f32 -> bf16
#pragma unroll
        for (int p = 0; p < 8; ++p) {
            int f   = p * 256 + tid;
            int row = f >> 4;
            int c4  = f & 15;
            int gr  = base + row;
            float4 v = make_float4(0.f, 0.f, 0.f, 0.f);
            if (gr < NNODES) v = *reinterpret_cast<const float4*>(&x[(size_t)gr * IND + k0 + c4 * 4]);
            uint2 pk;
            pk.x = (unsigned)f2bf(v.x) | ((unsigned)f2bf(v.y) << 16);
            pk.y = (unsigned)f2bf(v.z) | ((unsigned)f2bf(v.w) << 16);
            int byte = row * 128 + ((c4 * 8) ^ ((row & 7) << 4));
            *reinterpret_cast<uint2*>(&Al[byte]) = pk;
        }
        // stage B: 128 cols x 64 k from Wt (already bf16), coalesced 16B
#pragma unroll
        for (int p = 0; p < 4; ++p) {
            int f   = p * 256 + tid;
            int col = f >> 3;
            int k8  = f & 7;
            uint4 v = *reinterpret_cast<const uint4*>(&Wt[col * IND + k0 + k8 * 8]);
            int byte = col * 128 + ((k8 * 16) ^ ((col & 7) << 4));
            *reinterpret_cast<uint4*>(&Bl[byte]) = v;
        }
        __syncthreads();
#pragma unroll
        for (int ks = 0; ks < 2; ++ks) {
            bf16x8 af[4], bfr[4];
#pragma unroll
            for (int mt = 0; mt < 4; ++mt) {
                int row  = wr + mt * 16 + l15;
                int byte = row * 128 + ((ks * 64 + kg * 16) ^ ((row & 7) << 4));
                af[mt] = *reinterpret_cast<const bf16x8*>(&Al[byte]);
            }
#pragma unroll
            for (int nt = 0; nt < 4; ++nt) {
                int col  = wc + nt * 16 + l15;
                int byte = col * 128 + ((ks * 64 + kg * 16) ^ ((col & 7) << 4));
                bfr[nt] = *reinterpret_cast<const bf16x8*>(&Bl[byte]);
            }
#pragma unroll
            for (int mt = 0; mt < 4; ++mt)
#pragma unroll
                for (int nt = 0; nt < 4; ++nt)
                    acc[mt][nt] = __builtin_amdgcn_mfma_f32_16x16x32_bf16(af[mt], bfr[nt], acc[mt][nt], 0, 0, 0);
        }
        __syncthreads();
    }
    // C/D layout: col = lane&15, row = (lane>>4)*4 + q  [m89-verified]
#pragma unroll
    for (int mt = 0; mt < 4; ++mt) {
#pragma unroll
        for (int q = 0; q < 4; ++q) {
            int grow = base + wr + mt * 16 + kg * 4 + q;
            if (grow < NNODES) {
#pragma unroll
                for (int nt = 0; nt < 4; ++nt)
                    h[(size_t)grow * OUTD + wc + nt * 16 + l15] = acc[mt][nt][q];
            }
        }
    }
}

// ---------------- kernel 2: scores + segment softmax ----------------
// lane = edge_slot j (lane>>2, 16 edges/node) x dim_group g (lane&3).
// h rows staged in LDS, 16B-block XOR swizzle: blk' = blk ^ ((row&7)<<2).
__global__ __launch_bounds__(256) void edge_kernel(const float* __restrict__ h,
                                                   const float* __restrict__ a,
                                                   const int* __restrict__ eidx,
                                                   float* __restrict__ attn) {
    extern __shared__ __align__(16) unsigned char hl[];   // SROWS*512 = 73728 B

    const int tid  = threadIdx.x;
    const int base = blockIdx.x * NB;
    const int lane = tid & 63;
    const int wid  = tid >> 6;
    const int j    = lane >> 2;   // edge slot 0..15
    const int g    = lane & 3;    // dim group 0..3

    // preload a: lane's dims are {c*16 + g*4 .. +3} for c = 0..7
    float4 a4[8];
#pragma unroll
    for (int c = 0; c < 8; ++c)
        a4[c] = *reinterpret_cast<const float4*>(&a[c * 16 + g * 4]);

    // stage SROWS rows of h (wrap mod N), swizzled source so LDS reads are even
    for (int p = 0; p < 18; ++p) {
        int f    = p * 256 + tid;         // 4608 16B-slots
        int row  = f >> 5;
        int blkp = f & 31;
        int blk  = blkp ^ ((row & 7) << 2);
        int gr   = base + row;
        if (gr >= NNODES) gr -= NNODES;
        float4 v = *reinterpret_cast<const float4*>(&h[(size_t)gr * OUTD + blk * 4]);
        *reinterpret_cast<float4*>(&hl[f * 16]) = v;
    }
    __syncthreads();

    const int* cols = eidx + NEDGES;      // edge_index row 1
    for (int n = 0; n < 32; ++n) {
        int i = base + wid * 32 + n;
        if (i >= NNODES) break;           // wave-uniform
        int e   = i * DEG + j;
        int col = cols[e];
        int cr  = col - base;
        if (cr < 0) cr += NNODES;
        int ri = i - base;
        float s = 0.f;
        if (cr < SROWS) {                 // fast path (always taken for this graph)
#pragma unroll
            for (int c = 0; c < 8; ++c) {
                int blk = c * 4 + g;
                float4 hi = *reinterpret_cast<const float4*>(&hl[ri * 512 + ((blk ^ ((ri & 7) << 2)) * 16)]);
                float4 hj = *reinterpret_cast<const float4*>(&hl[cr * 512 + ((blk ^ ((cr & 7) << 2)) * 16)]);
                s = fmaf(fabsf(hi.x - hj.x), a4[c].x, s);
                s = fmaf(fabsf(hi.y - hj.y), a4[c].y, s);
                s = fmaf(fabsf(hi.z - hj.z), a4[c].z, s);
                s = fmaf(fabsf(hi.w - hj.w), a4[c].w, s);
            }
        } else {                          // general fallback: neighbor not staged
#pragma unroll
            for (int c = 0; c < 8; ++c) {
                int blk = c * 4 + g;
                float4 hi = *reinterpret_cast<const float4*>(&hl[ri * 512 + ((blk ^ ((ri & 7) << 2)) * 16)]);
                float4 hj = *reinterpret_cast<const float4*>(&h[(size_t)col * OUTD + blk * 4]);
                s = fmaf(fabsf(hi.x - hj.x), a4[c].x, s);
                s = fmaf(fabsf(hi.y - hj.y), a4[c].y, s);
                s = fmaf(fabsf(hi.z - hj.z), a4[c].z, s);
                s = fmaf(fabsf(hi.w - hj.w), a4[c].w, s);
            }
        }
        // combine the 4 dim-groups of this edge
        s += __shfl_xor(s, 1);
        s += __shfl_xor(s, 2);
        s = fmaxf(s, 0.f);                // relu
        // segment softmax across the 16 edge groups (values replicated x4)
        float m = s;
        m = fmaxf(m, __shfl_xor(m, 4));
        m = fmaxf(m, __shfl_xor(m, 8));
        m = fmaxf(m, __shfl_xor(m, 16));
        m = fmaxf(m, __shfl_xor(m, 32));
        float pv = __expf(s - m);
        float S = pv;
        S += __shfl_xor(S, 4);
        S += __shfl_xor(S, 8);
        S += __shfl_xor(S, 16);
        S += __shfl_xor(S, 32);
        if (g == 0) attn[e] = pv / S;
    }
}

extern "C" void kernel_launch(void* const* d_in, const int* in_sizes, int n_in,
                              void* d_out, int out_size, void* d_ws, size_t ws_size,
                              hipStream_t stream) {
    const float* x  = (const float*)d_in[0];
    const float* W  = (const float*)d_in[1];
    const float* a  = (const float*)d_in[2];
    const int* eidx = (const int*)d_in[3];
    float* h    = (float*)d_out;
    float* attn = h + (size_t)NNODES * OUTD;
    unsigned short* Wt = (unsigned short*)d_ws;   // 128 KB scratch

    hipLaunchKernelGGL(wt_kernel, dim3(64), dim3(256), 0, stream, W, Wt);
    hipLaunchKernelGGL(gemm_kernel, dim3((NNODES + BM - 1) / BM), dim3(256), 0, stream, x, Wt, h);
    hipLaunchKernelGGL(edge_kernel, dim3((NNODES + NB - 1) / NB), dim3(256), SROWS * 512, stream,
                       h, a, eidx, attn);
}

// Round 2
// 80.331 us; speedup vs baseline: 1.0222x; 1.0222x over previous
//
#include <hip/hip_runtime.h>
#include <hip/hip_bf16.h>

#define NNODES 50000
#define DEG 16
#define NEDGES (NNODES * DEG)
#define IND 512
#define OUTD 128

#define BM 32           // gemm rows per block (full 128 cols per block)
#define NB 64           // nodes per block in edge kernel
#define SROWS 80        // staged h rows per block (NB + DEG)

typedef __attribute__((ext_vector_type(8))) short bf16x8;
typedef __attribute__((ext_vector_type(4))) float f32x4;

static __device__ __forceinline__ unsigned short f2bf(float f) {
    unsigned u = __builtin_bit_cast(unsigned, f);
    u += 0x7fffu + ((u >> 16) & 1u);
    return (unsigned short)(u >> 16);
}

// ---------------- kernel 0: W [512][128] f32 -> Wt [128][512] bf16 ----------------
__global__ __launch_bounds__(256) void wt_kernel(const float* __restrict__ W,
                                                 unsigned short* __restrict__ Wt) {
    int flat = blockIdx.x * 256 + threadIdx.x;   // 16384 = 128 n * 128 k4
    int n  = flat >> 7;
    int k4 = flat & 127;
    int k0 = k4 * 4;
    unsigned short v0 = f2bf(W[(k0 + 0) * OUTD + n]);
    unsigned short v1 = f2bf(W[(k0 + 1) * OUTD + n]);
    unsigned short v2 = f2bf(W[(k0 + 2) * OUTD + n]);
    unsigned short v3 = f2bf(W[(k0 + 3) * OUTD + n]);
    uint2 o;
    o.x = (unsigned)v0 | ((unsigned)v1 << 16);
    o.y = (unsigned)v2 | ((unsigned)v3 << 16);
    *reinterpret_cast<uint2*>(&Wt[n * IND + k0]) = o;
}

// ---------------- kernel 1: h = x @ W  (bf16 MFMA, f32 accum) ----------------
// block: 256 thr (4 waves). Tile 32 rows x 128 cols; wave w owns cols w*32..+31.
// K split in 2 halves of 256. B frags preloaded to regs from L2-hot Wt;
// A staged f32->bf16 in LDS, XOR-swizzled (byte ^= (row&7)<<4).
__global__ __launch_bounds__(256) void gemm_kernel(const float* __restrict__ x,
                                                   const unsigned short* __restrict__ Wt,
                                                   float* __restrict__ h) {
    __shared__ __align__(16) unsigned char Al[BM * 256 * 2];   // 16 KB (rows x 256k bf16)

    const int tid  = threadIdx.x;
    const int base = blockIdx.x * BM;
    const int lane = tid & 63;
    const int wid  = tid >> 6;
    const int wc   = wid * 32;          // wave's col base
    const int l15  = lane & 15;
    const int kg   = lane >> 4;

    f32x4 zero = {0.f, 0.f, 0.f, 0.f};
    f32x4 acc[2][2];
#pragma unroll
    for (int mt = 0; mt < 2; ++mt)
#pragma unroll
        for (int nt = 0; nt < 2; ++nt) acc[mt][nt] = zero;

#pragma unroll
    for (int half = 0; half < 2; ++half) {
        const int k0 = half * 256;

        // preload B fragments for this K-half: 2 col-tiles x 8 k-steps (L2-hot)
        bf16x8 bfr[2][8];
#pragma unroll
        for (int nt = 0; nt < 2; ++nt) {
            const unsigned short* bp = &Wt[(size_t)(wc + nt * 16 + l15) * IND + k0 + kg * 8];
#pragma unroll
            for (int ks = 0; ks < 8; ++ks)
                bfr[nt][ks] = *reinterpret_cast<const bf16x8*>(bp + ks * 32);
        }

        // stage A: 32 rows x 256 k, f32 -> bf16, coalesced float4 reads
#pragma unroll
        for (int p = 0; p < 8; ++p) {
            int f   = p * 256 + tid;       // 2048 float4 slots = 32 rows x 64
            int row = f >> 6;
            int s4  = f & 63;
            int gr  = base + row;
            float4 v = make_float4(0.f, 0.f, 0.f, 0.f);
            if (gr < NNODES) v = *reinterpret_cast<const float4*>(&x[(size_t)gr * IND + k0 + s4 * 4]);
            uint2 pk;
            pk.x = (unsigned)f2bf(v.x) | ((unsigned)f2bf(v.y) << 16);
            pk.y = (unsigned)f2bf(v.z) | ((unsigned)f2bf(v.w) << 16);
            int byte = row * 512 + ((s4 * 8) ^ ((row & 7) << 4));
            *reinterpret_cast<uint2*>(&Al[byte]) = pk;
        }
        __syncthreads();

#pragma unroll
        for (int ks = 0; ks < 8; ++ks) {
            bf16x8 af[2];
#pragma unroll
            for (int mt = 0; mt < 2; ++mt) {
                int row  = mt * 16 + l15;
                int byte = row * 512 + ((ks * 64 + kg * 16) ^ ((row & 7) << 4));
                af[mt] = *reinterpret_cast<const bf16x8*>(&Al[byte]);
            }
#pragma unroll
            for (int mt = 0; mt < 2; ++mt)
#pragma unroll
                for (int nt = 0; nt < 2; ++nt)
                    acc[mt][nt] = __builtin_amdgcn_mfma_f32_16x16x32_bf16(af[mt], bfr[nt][ks], acc[mt][nt], 0, 0, 0);
        }
        __syncthreads();
    }

    // C/D layout: col = lane&15, row = (lane>>4)*4 + q
#pragma unroll
    for (int mt = 0; mt < 2; ++mt) {
#pragma unroll
        for (int q = 0; q < 4; ++q) {
            int grow = base + mt * 16 + kg * 4 + q;
            if (grow < NNODES) {
#pragma unroll
                for (int nt = 0; nt < 2; ++nt)
                    h[(size_t)grow * OUTD + wc + nt * 16 + l15] = acc[mt][nt][q];
            }
        }
    }
}

// ---------------- kernel 2: scores + segment softmax ----------------
// lane = edge_slot j (lane>>2) x dim_group g (lane&3); wave handles 16 nodes.
// h rows staged in LDS, 16B-block XOR swizzle: blk' = blk ^ ((row&7)<<2).
__global__ __launch_bounds__(256) void edge_kernel(const float* __restrict__ h,
                                                   const float* __restrict__ a,
                                                   const int* __restrict__ eidx,
                                                   float* __restrict__ attn) {
    extern __shared__ __align__(16) unsigned char hl[];   // SROWS*512 = 40960 B

    const int tid  = threadIdx.x;
    const int base = blockIdx.x * NB;
    const int lane = tid & 63;
    const int wid  = tid >> 6;
    const int j    = lane >> 2;   // edge slot 0..15
    const int g    = lane & 3;    // dim group 0..3

    float4 a4[8];
#pragma unroll
    for (int c = 0; c < 8; ++c)
        a4[c] = *reinterpret_cast<const float4*>(&a[c * 16 + g * 4]);

    // stage SROWS rows of h (wrap mod N), swizzled so per-row reads hit all banks
    for (int p = 0; p < 10; ++p) {
        int f    = p * 256 + tid;         // 2560 16B-slots
        int row  = f >> 5;
        int blkp = f & 31;
        int blk  = blkp ^ ((row & 7) << 2);
        int gr   = base + row;
        if (gr >= NNODES) gr -= NNODES;
        float4 v = *reinterpret_cast<const float4*>(&h[(size_t)gr * OUTD + blk * 4]);
        *reinterpret_cast<float4*>(&hl[f * 16]) = v;
    }
    __syncthreads();

    const int* cols = eidx + NEDGES;      // edge_index row 1
    for (int n = 0; n < 16; ++n) {
        int i = base + wid * 16 + n;
        if (i >= NNODES) break;           // wave-uniform
        int e   = i * DEG + j;
        int col = cols[e];
        int cr  = col - base;
        if (cr < 0) cr += NNODES;
        int ri = i - base;
        float s = 0.f;
        if (cr < SROWS) {                 // fast path (always taken for this graph)
#pragma unroll
            for (int c = 0; c < 8; ++c) {
                int blk = c * 4 + g;
                float4 hi = *reinterpret_cast<const float4*>(&hl[ri * 512 + ((blk ^ ((ri & 7) << 2)) * 16)]);
                float4 hj = *reinterpret_cast<const float4*>(&hl[cr * 512 + ((blk ^ ((cr & 7) << 2)) * 16)]);
                s = fmaf(fabsf(hi.x - hj.x), a4[c].x, s);
                s = fmaf(fabsf(hi.y - hj.y), a4[c].y, s);
                s = fmaf(fabsf(hi.z - hj.z), a4[c].z, s);
                s = fmaf(fabsf(hi.w - hj.w), a4[c].w, s);
            }
        } else {                          // general fallback: neighbor not staged
#pragma unroll
            for (int c = 0; c < 8; ++c) {
                int blk = c * 4 + g;
                float4 hi = *reinterpret_cast<const float4*>(&hl[ri * 512 + ((blk ^ ((ri & 7) << 2)) * 16)]);
                float4 hj = *reinterpret_cast<const float4*>(&h[(size_t)col * OUTD + blk * 4]);
                s = fmaf(fabsf(hi.x - hj.x), a4[c].x, s);
                s = fmaf(fabsf(hi.y - hj.y), a4[c].y, s);
                s = fmaf(fabsf(hi.z - hj.z), a4[c].z, s);
                s = fmaf(fabsf(hi.w - hj.w), a4[c].w, s);
            }
        }
        s += __shfl_xor(s, 1);
        s += __shfl_xor(s, 2);
        s = fmaxf(s, 0.f);                // relu
        float m = s;
        m = fmaxf(m, __shfl_xor(m, 4));
        m = fmaxf(m, __shfl_xor(m, 8));
        m = fmaxf(m, __shfl_xor(m, 16));
        m = fmaxf(m, __shfl_xor(m, 32));
        float pv = __expf(s - m);
        float S = pv;
        S += __shfl_xor(S, 4);
        S += __shfl_xor(S, 8);
        S += __shfl_xor(S, 16);
        S += __shfl_xor(S, 32);
        if (g == 0) attn[e] = pv / S;
    }
}

extern "C" void kernel_launch(void* const* d_in, const int* in_sizes, int n_in,
                              void* d_out, int out_size, void* d_ws, size_t ws_size,
                              hipStream_t stream) {
    const float* x  = (const float*)d_in[0];
    const float* W  = (const float*)d_in[1];
    const float* a  = (const float*)d_in[2];
    const int* eidx = (const int*)d_in[3];
    float* h    = (float*)d_out;
    float* attn = h + (size_t)NNODES * OUTD;
    unsigned short* Wt = (unsigned short*)d_ws;   // 128 KB scratch

    hipLaunchKernelGGL(wt_kernel, dim3(64), dim3(256), 0, stream, W, Wt);
    hipLaunchKernelGGL(gemm_kernel, dim3((NNODES + BM - 1) / BM), dim3(256), 0, stream, x, Wt, h);
    hipLaunchKernelGGL(edge_kernel, dim3((NNODES + NB - 1) / NB), dim3(256), SROWS * 512, stream,
                       h, a, eidx, attn);
}

// Round 3
// 70.789 us; speedup vs baseline: 1.1600x; 1.1348x over previous
//
#include <hip/hip_runtime.h>
#include <hip/hip_bf16.h>

#define NNODES 50000
#define DEG 16
#define NEDGES (NNODES * DEG)
#define IND 512
#define OUTD 128

#define BM 32           // gemm rows per block (full 128 cols)
#define CK 64           // K chunk
#define NCH 8           // 512 / 64
#define NB 64           // nodes per block in edge kernel
#define SROWS 80        // staged h rows per block (NB + DEG)

typedef __attribute__((ext_vector_type(8))) short bf16x8;
typedef __attribute__((ext_vector_type(4))) float f32x4;

static __device__ __forceinline__ unsigned short f2bf(float f) {
    unsigned u = __builtin_bit_cast(unsigned, f);
    u += 0x7fffu + ((u >> 16) & 1u);
    return (unsigned short)(u >> 16);
}

static __device__ __forceinline__ bf16x8 pack8(float4 a, float4 b) {
    union { unsigned u[4]; bf16x8 v; } r;
    r.u[0] = (unsigned)f2bf(a.x) | ((unsigned)f2bf(a.y) << 16);
    r.u[1] = (unsigned)f2bf(a.z) | ((unsigned)f2bf(a.w) << 16);
    r.u[2] = (unsigned)f2bf(b.x) | ((unsigned)f2bf(b.y) << 16);
    r.u[3] = (unsigned)f2bf(b.z) | ((unsigned)f2bf(b.w) << 16);
    return r.v;
}

// ---------------- kernel 0: W [512][128] f32 -> Wt [128][512] bf16 ----------------
__global__ __launch_bounds__(256) void wt_kernel(const float* __restrict__ W,
                                                 unsigned short* __restrict__ Wt) {
    int flat = blockIdx.x * 256 + threadIdx.x;   // 16384 = 128 n * 128 k4
    int n  = flat >> 7;
    int k4 = flat & 127;
    int k0 = k4 * 4;
    unsigned short v0 = f2bf(W[(k0 + 0) * OUTD + n]);
    unsigned short v1 = f2bf(W[(k0 + 1) * OUTD + n]);
    unsigned short v2 = f2bf(W[(k0 + 2) * OUTD + n]);
    unsigned short v3 = f2bf(W[(k0 + 3) * OUTD + n]);
    uint2 o;
    o.x = (unsigned)v0 | ((unsigned)v1 << 16);
    o.y = (unsigned)v2 | ((unsigned)v3 << 16);
    *reinterpret_cast<uint2*>(&Wt[n * IND + k0]) = o;
}

// ---------------- kernel 1: h = x @ W  (bf16 MFMA, f32 accum) ----------------
// Tile 32 rows x 128 cols, K chunks of 64, double-buffered LDS via global_load_lds.
// A staged as RAW f32 (convert on read side); B staged bf16 from Wt.
// Swizzle: LDS dest linear, global SOURCE pre-swizzled per 16B granule (g ^= row&7),
// reads apply the same XOR (rule #21 both-sides).
// LDS: A 2x[32][64]f32 = 16 KB @0, B 2x[128][64]bf16 = 32 KB @16384. Total 48 KB.
__global__ __launch_bounds__(256, 3) void gemm_kernel(const float* __restrict__ x,
                                                      const unsigned short* __restrict__ Wt,
                                                      float* __restrict__ h) {
    __shared__ __align__(16) unsigned char lds_[49152];

    const int tid  = threadIdx.x;
    const int lane = tid & 63;
    const int wid  = tid >> 6;
    const int l15  = lane & 15;
    const int kg   = lane >> 4;

    // bijective XCD swizzle (m204)
    const int nwg = gridDim.x;
    const int q8  = nwg >> 3, r8 = nwg & 7;
    const int xcd = blockIdx.x & 7, idx = blockIdx.x >> 3;
    const int swz = (xcd < r8 ? xcd * (q8 + 1) : r8 * (q8 + 1) + (xcd - r8) * q8) + idx;
    const int base = swz * BM;

    const int rb = (wid >> 1) * 16;   // wave's row sub-tile
    const int cb = (wid & 1) * 64;    // wave's col sub-tile

    f32x4 acc[4];
#pragma unroll
    for (int nt = 0; nt < 4; ++nt) acc[nt] = (f32x4){0.f, 0.f, 0.f, 0.f};

    auto stage = [&](int buf, int ch) {
        // 24 wave-instrs per chunk: 8 A (8 KB f32) + 16 B (16 KB bf16); 6 per wave
        for (int i = wid; i < 24; i += 4) {
            if (i < 8) {
                int row   = i * 4 + (lane >> 4);
                int lg    = (lane & 15) ^ (row & 7);        // pre-swizzled source granule
                int grow  = base + row; if (grow > NNODES - 1) grow = NNODES - 1;
                const float* gp = &x[(size_t)grow * IND + ch * CK + lg * 4];
                unsigned char* lp = &lds_[buf * 8192 + i * 1024];
                __builtin_amdgcn_global_load_lds((const unsigned int*)gp, (unsigned int*)lp, 16, 0, 0);
            } else {
                int i2  = i - 8;
                int col = i2 * 8 + (lane >> 3);
                int lg  = (lane & 7) ^ (col & 7);
                const unsigned short* gp = &Wt[(size_t)col * IND + ch * CK + lg * 8];
                unsigned char* lp = &lds_[16384 + buf * 16384 + i2 * 1024];
                __builtin_amdgcn_global_load_lds((const unsigned int*)gp, (unsigned int*)lp, 16, 0, 0);
            }
        }
    };

    stage(0, 0);
    __syncthreads();

    int buf = 0;
    for (int ch = 0; ch < NCH; ++ch) {
        if (ch < NCH - 1) stage(buf ^ 1, ch + 1);   // prefetch overlaps compute below

#pragma unroll
        for (int ks = 0; ks < 2; ++ks) {
            // A frag: rows rb+l15, k = ks*32 + kg*8 .. +7 (two swizzled f32 granules)
            int arow = rb + l15;
            int s1   = (ks * 8 + kg * 2) ^ (arow & 7);
            const unsigned char* ab = &lds_[buf * 8192 + arow * 256];
            float4 a1 = *reinterpret_cast<const float4*>(ab + s1 * 16);
            float4 a2 = *reinterpret_cast<const float4*>(ab + (s1 ^ 1) * 16);
            bf16x8 af = pack8(a1, a2);
#pragma unroll
            for (int nt = 0; nt < 4; ++nt) {
                int col = cb + nt * 16 + l15;
                int sB  = (ks * 4 + kg) ^ (col & 7);
                bf16x8 bv = *reinterpret_cast<const bf16x8*>(
                    &lds_[16384 + buf * 16384 + col * 128 + sB * 16]);
                acc[nt] = __builtin_amdgcn_mfma_f32_16x16x32_bf16(af, bv, acc[nt], 0, 0, 0);
            }
        }
        __syncthreads();   // drains vmcnt (prefetch had full compute phase) + barrier
        buf ^= 1;
    }

    // C/D layout: col = lane&15, row = (lane>>4)*4 + q
#pragma unroll
    for (int nt = 0; nt < 4; ++nt) {
#pragma unroll
        for (int q = 0; q < 4; ++q) {
            int grow = base + rb + kg * 4 + q;
            if (grow < NNODES)
                h[(size_t)grow * OUTD + cb + nt * 16 + l15] = acc[nt][q];
        }
    }
}

// ---------------- kernel 2: scores + segment softmax ----------------
__global__ __launch_bounds__(256) void edge_kernel(const float* __restrict__ h,
                                                   const float* __restrict__ a,
                                                   const int* __restrict__ eidx,
                                                   float* __restrict__ attn) {
    extern __shared__ __align__(16) unsigned char hl[];   // SROWS*512 = 40960 B

    const int tid  = threadIdx.x;
    const int base = blockIdx.x * NB;
    const int lane = tid & 63;
    const int wid  = tid >> 6;
    const int j    = lane >> 2;   // edge slot 0..15
    const int g    = lane & 3;    // dim group 0..3

    float4 a4[8];
#pragma unroll
    for (int c = 0; c < 8; ++c)
        a4[c] = *reinterpret_cast<const float4*>(&a[c * 16 + g * 4]);

    for (int p = 0; p < 10; ++p) {
        int f    = p * 256 + tid;         // 2560 16B-slots
        int row  = f >> 5;
        int blkp = f & 31;
        int blk  = blkp ^ ((row & 7) << 2);
        int gr   = base + row;
        if (gr >= NNODES) gr -= NNODES;
        float4 v = *reinterpret_cast<const float4*>(&h[(size_t)gr * OUTD + blk * 4]);
        *reinterpret_cast<float4*>(&hl[f * 16]) = v;
    }
    __syncthreads();

    const int* cols = eidx + NEDGES;
    for (int n = 0; n < 16; ++n) {
        int i = base + wid * 16 + n;
        if (i >= NNODES) break;           // wave-uniform
        int e   = i * DEG + j;
        int col = cols[e];
        int cr  = col - base;
        if (cr < 0) cr += NNODES;
        int ri = i - base;
        float s = 0.f;
        if (cr < SROWS) {
#pragma unroll
            for (int c = 0; c < 8; ++c) {
                int blk = c * 4 + g;
                float4 hi = *reinterpret_cast<const float4*>(&hl[ri * 512 + ((blk ^ ((ri & 7) << 2)) * 16)]);
                float4 hj = *reinterpret_cast<const float4*>(&hl[cr * 512 + ((blk ^ ((cr & 7) << 2)) * 16)]);
                s = fmaf(fabsf(hi.x - hj.x), a4[c].x, s);
                s = fmaf(fabsf(hi.y - hj.y), a4[c].y, s);
                s = fmaf(fabsf(hi.z - hj.z), a4[c].z, s);
                s = fmaf(fabsf(hi.w - hj.w), a4[c].w, s);
            }
        } else {
#pragma unroll
            for (int c = 0; c < 8; ++c) {
                int blk = c * 4 + g;
                float4 hi = *reinterpret_cast<const float4*>(&hl[ri * 512 + ((blk ^ ((ri & 7) << 2)) * 16)]);
                float4 hj = *reinterpret_cast<const float4*>(&h[(size_t)col * OUTD + blk * 4]);
                s = fmaf(fabsf(hi.x - hj.x), a4[c].x, s);
                s = fmaf(fabsf(hi.y - hj.y), a4[c].y, s);
                s = fmaf(fabsf(hi.z - hj.z), a4[c].z, s);
                s = fmaf(fabsf(hi.w - hj.w), a4[c].w, s);
            }
        }
        s += __shfl_xor(s, 1);
        s += __shfl_xor(s, 2);
        s = fmaxf(s, 0.f);
        float m = s;
        m = fmaxf(m, __shfl_xor(m, 4));
        m = fmaxf(m, __shfl_xor(m, 8));
        m = fmaxf(m, __shfl_xor(m, 16));
        m = fmaxf(m, __shfl_xor(m, 32));
        float pv = __expf(s - m);
        float S = pv;
        S += __shfl_xor(S, 4);
        S += __shfl_xor(S, 8);
        S += __shfl_xor(S, 16);
        S += __shfl_xor(S, 32);
        if (g == 0) attn[e] = pv / S;
    }
}

extern "C" void kernel_launch(void* const* d_in, const int* in_sizes, int n_in,
                              void* d_out, int out_size, void* d_ws, size_t ws_size,
                              hipStream_t stream) {
    const float* x  = (const float*)d_in[0];
    const float* W  = (const float*)d_in[1];
    const float* a  = (const float*)d_in[2];
    const int* eidx = (const int*)d_in[3];
    float* h    = (float*)d_out;
    float* attn = h + (size_t)NNODES * OUTD;
    unsigned short* Wt = (unsigned short*)d_ws;   // 128 KB scratch

    hipLaunchKernelGGL(wt_kernel, dim3(64), dim3(256), 0, stream, W, Wt);
    hipLaunchKernelGGL(gemm_kernel, dim3((NNODES + BM - 1) / BM), dim3(256), 0, stream, x, Wt, h);
    hipLaunchKernelGGL(edge_kernel, dim3((NNODES + NB - 1) / NB), dim3(256), SROWS * 512, stream,
                       h, a, eidx, attn);
}